// Round 1
// baseline (507.946 us; speedup 1.0000x reference)
//
#include <hip/hip_runtime.h>
#include <hip/hip_bf16.h>
#include <math.h>

#define BN 4096
#define LH 200
#define LFB 100
#define ED 64
#define PD 32
#define HD 32
#define NP 3168   // P + PNET = 32 + 3136

// ws layout (floats)
#define WS_FUE 0                          // final_user_embed B*64
#define WS_FIE (WS_FUE + BN*ED)           // final_item_embed B*64
#define WS_PIN (WS_FIE + BN*ED)           // prompt_input B*64
#define WS_TP  (WS_PIN + BN*ED)           // total_prompt B*3168
#define WS_PPE (WS_TP + (size_t)BN*NP)    // pos_pe B*32

// ---------------------------------------------------------------------------
// Kernel 1: per-batch gathers, feature embeds, attention softmax pooling,
// pos-feedback masked mean.  grid=B, block=256.
// ---------------------------------------------------------------------------
__global__ __launch_bounds__(256) void k1_gather_attn(
    const float* __restrict__ item_emb, const float* __restrict__ user_emb,
    const float* __restrict__ W_if, const float* __restrict__ b_if,
    const float* __restrict__ W_uf, const float* __restrict__ b_uf,
    const float* __restrict__ item_features, const float* __restrict__ user_features,
    const int* __restrict__ user_id, const int* __restrict__ target_item_id,
    const int* __restrict__ hist_id, const int* __restrict__ hist_len,
    const int* __restrict__ pos_fb, const int* __restrict__ pos_mask,
    float* __restrict__ FUE, float* __restrict__ FIE, float* __restrict__ PIN)
{
    const int b = blockIdx.x;
    const int t = threadIdx.x;
    __shared__ __align__(16) float tgt[64];
    __shared__ float feats[256];
    __shared__ float ufe[64];
    __shared__ float attn[256];
    __shared__ float red[256];
    __shared__ float part[4*64];
    __shared__ float cntw[4];
    __shared__ float pooled[64];

    const int tid_item = target_item_id[b];
    feats[t] = (t < 128) ? item_features[(size_t)b*128 + t]
                         : user_features[(size_t)b*128 + (t-128)];
    if (t < 64) tgt[t] = item_emb[(size_t)tid_item*64 + t];
    __syncthreads();

    // feature embeddings (sigmoid(x@W + b))
    if (t < 128) {
        const int e = t & 63;
        const float* W  = (t < 64) ? W_if : W_uf;
        const float* bb = (t < 64) ? b_if : b_uf;
        const float* fr = (t < 64) ? feats : (feats + 128);
        float acc = bb[e];
        #pragma unroll 4
        for (int k = 0; k < 128; k++) acc = fmaf(fr[k], W[k*64 + e], acc);
        float s = 1.f / (1.f + expf(-acc));
        if (t < 64) FIE[(size_t)b*64 + e] = tgt[e] + s;
        else        ufe[e] = s;
    }

    // attention scores
    const int hl = hist_len[b];
    float sc = -1e9f;
    if (t < LH && t < hl) {
        const int idx = hist_id[(size_t)b*LH + t];
        const float4* hp = (const float4*)(item_emb + (size_t)idx*64);
        const float4* tp = (const float4*)tgt;
        float acc = 0.f;
        #pragma unroll
        for (int i = 0; i < 16; i++) {
            float4 h4 = hp[i]; float4 t4 = tp[i];
            acc += h4.x*t4.x + h4.y*t4.y + h4.z*t4.z + h4.w*t4.w;
        }
        sc = acc * 0.125f;
    }
    red[t] = sc;
    __syncthreads();
    #pragma unroll
    for (int s = 128; s > 0; s >>= 1) {
        if (t < s) red[t] = fmaxf(red[t], red[t+s]);
        __syncthreads();
    }
    const float mx = red[0];
    __syncthreads();
    const float ev = expf(sc - mx);   // invalid lanes: exp(-1e9 - mx) -> 0
    red[t] = ev;
    __syncthreads();
    #pragma unroll
    for (int s = 128; s > 0; s >>= 1) {
        if (t < s) red[t] += red[t+s];
        __syncthreads();
    }
    const float S = red[0];
    __syncthreads();
    attn[t] = ev / S;
    __syncthreads();

    // pooled = sum_l attn[l] * hist[l][e], 4-way l-split
    const int w = t >> 6, e = t & 63;
    {
        float acc = 0.f;
        #pragma unroll 2
        for (int l = w; l < LH; l += 4) {
            const int idx = hist_id[(size_t)b*LH + l];
            acc = fmaf(attn[l], item_emb[(size_t)idx*64 + e], acc);
        }
        part[w*64 + e] = acc;
    }
    __syncthreads();
    if (t < 64) pooled[t] = part[t] + part[64+t] + part[128+t] + part[192+t];
    __syncthreads();

    // pos-feedback masked mean
    {
        float acc = 0.f, cnt = 0.f;
        #pragma unroll 2
        for (int l = w; l < LFB; l += 4) {
            const int mv  = pos_mask[(size_t)b*LFB + l];
            const int idx = pos_fb[(size_t)b*LFB + l];
            if (mv) { acc += item_emb[(size_t)idx*64 + e]; cnt += 1.f; }
        }
        part[w*64 + e] = acc;
        if (e == 0) cntw[w] = cnt;
    }
    __syncthreads();
    if (t < 64) {
        const float c = cntw[0] + cntw[1] + cntw[2] + cntw[3];
        PIN[(size_t)b*64 + t] = (part[t] + part[64+t] + part[128+t] + part[192+t]) / c;
        FUE[(size_t)b*64 + t] = user_emb[(size_t)user_id[b]*64 + t] + ufe[t] + pooled[t];
    }
}

// ---------------------------------------------------------------------------
// Kernel 2: total_prompt = relu(PIN (4096x64) @ Wp (64x3168) + bp)
// tile 64(m) x 128(n), K=64, 256 threads, 4x8 per thread. grid=(25,64)
// ---------------------------------------------------------------------------
__global__ __launch_bounds__(256) void k2_prompt_gemm(
    const float* __restrict__ PIN, const float* __restrict__ Wp,
    const float* __restrict__ bp, float* __restrict__ TP)
{
    __shared__ __align__(16) float As[64*65];    // [m][k], ld 65
    __shared__ __align__(16) float Bs[64*128];   // [k][n]
    const int t = threadIdx.x;
    const int m0 = blockIdx.y * 64;
    const int n0 = blockIdx.x * 128;
    {
        const int k = t & 63, ml = t >> 6;
        #pragma unroll
        for (int i = 0; i < 16; i++) {
            const int m = ml + i*4;
            As[m*65 + k] = PIN[(size_t)(m0+m)*64 + k];
        }
    }
    {
        const int n = t & 127, kl = t >> 7;
        const int gn = n0 + n;
        #pragma unroll
        for (int i = 0; i < 32; i++) {
            const int k = kl + i*2;
            Bs[k*128 + n] = (gn < NP) ? Wp[(size_t)k*NP + gn] : 0.f;
        }
    }
    __syncthreads();
    const int tx = t & 15, ty = t >> 4;
    float acc[4][8];
    #pragma unroll
    for (int i = 0; i < 4; i++)
        #pragma unroll
        for (int j = 0; j < 8; j++) acc[i][j] = 0.f;

    #pragma unroll 4
    for (int k = 0; k < 64; k++) {
        float a[4];
        #pragma unroll
        for (int i = 0; i < 4; i++) a[i] = As[(ty*4+i)*65 + k];
        const float4 b0 = *(const float4*)&Bs[k*128 + tx*8];
        const float4 b1 = *(const float4*)&Bs[k*128 + tx*8 + 4];
        #pragma unroll
        for (int i = 0; i < 4; i++) {
            acc[i][0] = fmaf(a[i], b0.x, acc[i][0]);
            acc[i][1] = fmaf(a[i], b0.y, acc[i][1]);
            acc[i][2] = fmaf(a[i], b0.z, acc[i][2]);
            acc[i][3] = fmaf(a[i], b0.w, acc[i][3]);
            acc[i][4] = fmaf(a[i], b1.x, acc[i][4]);
            acc[i][5] = fmaf(a[i], b1.y, acc[i][5]);
            acc[i][6] = fmaf(a[i], b1.z, acc[i][6]);
            acc[i][7] = fmaf(a[i], b1.w, acc[i][7]);
        }
    }
    #pragma unroll
    for (int i = 0; i < 4; i++) {
        const int m = m0 + ty*4 + i;
        #pragma unroll
        for (int j = 0; j < 8; j++) {
            const int n = n0 + tx*8 + j;
            if (n < NP) TP[(size_t)m*NP + n] = fmaxf(acc[i][j] + bp[n], 0.f);
        }
    }
}

// ---------------------------------------------------------------------------
// Kernel 3: prompt hypernetwork MLP over pos+neg feedback, masked sums,
// loss output.  grid=B, block=256.  Weights are block-uniform -> s_load.
// thread t<100: pos item t; 128<=t<228: neg item t-128.
// ---------------------------------------------------------------------------
__global__ __launch_bounds__(256) void k3_prompt_mlp(
    const float* __restrict__ item_emb,
    const int* __restrict__ pos_fb, const int* __restrict__ pos_mask,
    const int* __restrict__ neg_fb, const int* __restrict__ neg_mask,
    const float* __restrict__ TP,
    float* __restrict__ POS_PE, float* __restrict__ out)
{
    const int b = blockIdx.x;
    const int t = threadIdx.x;
    __shared__ float scratch[256*33];
    const float* pn = TP + (size_t)b*NP + 32;   // pnet row (block-uniform)

    const bool isPos = (t < LFB);
    const bool isNeg = (t >= 128 && t < 128 + LFB);
    int active = 0, idx = 0;
    if (isPos) {
        const int li = t;
        active = (pos_mask[(size_t)b*LFB + li] != 0);
        idx = pos_fb[(size_t)b*LFB + li];
    } else if (isNeg) {
        const int li = t - 128;
        active = (neg_mask[(size_t)b*LFB + li] != 0);
        idx = neg_fb[(size_t)b*LFB + li];
    }
    const float4* up = (const float4*)(item_emb + (size_t)idx*64);

    // layer 1: h[e] = relu(sum_k u[k]*w1[k][e] + b1[e]); w1[k][e]=pn[k*32+e]
    float h[32];
    #pragma unroll
    for (int e = 0; e < 32; e++) h[e] = pn[2048 + e];   // b1
    for (int kc = 0; kc < 16; kc++) {
        float4 uv = make_float4(0.f, 0.f, 0.f, 0.f);
        if (active) uv = up[kc];
        const float us[4] = {uv.x, uv.y, uv.z, uv.w};
        #pragma unroll
        for (int j = 0; j < 4; j++) {
            const float uk = us[j];
            const float* wr = pn + (kc*4 + j)*32;
            #pragma unroll
            for (int e = 0; e < 32; e++) h[e] = fmaf(uk, wr[e], h[e]);
        }
    }
    #pragma unroll
    for (int e = 0; e < 32; e++) h[e] = fmaxf(h[e], 0.f);

    // layer 2: o[p] = sum_e h[e]*w2[e][p] + b2[p]; w2[e][p]=pn[2080+e*32+p]
    float o[32];
    #pragma unroll
    for (int p = 0; p < 32; p++) o[p] = pn[3104 + p];   // b2
    #pragma unroll
    for (int e = 0; e < 32; e++) {
        const float he = h[e];
        const float* wr = pn + 2080 + e*32;
        #pragma unroll
        for (int p = 0; p < 32; p++) o[p] = fmaf(he, wr[p], o[p]);
    }

    #pragma unroll
    for (int p = 0; p < 32; p++) scratch[t*33 + p] = active ? o[p] : 0.f;
    __syncthreads();

    // tree-reduce rows: pos region rows 0..127, neg region rows 128..255
    #pragma unroll
    for (int s = 64; s >= 1; s >>= 1) {
        const int chunk = s * 32;
        for (int i = t; i < 2*chunk; i += 256) {
            const int region = (i >= chunk) ? 1 : 0;
            const int rem = i - region*chunk;
            const int r = (rem >> 5) + region*128;
            const int p = rem & 31;
            scratch[r*33 + p] += scratch[(r+s)*33 + p];
        }
        __syncthreads();
    }
    if (t < 32) {
        const float pp = scratch[t];
        const float np = scratch[128*33 + t];
        POS_PE[(size_t)b*32 + t] = pp;
        const float x = np - pp;                       // -(pos - neg)
        out[BN + (size_t)b*32 + t] = fmaxf(x, 0.f) + log1pf(expf(-fabsf(x)));
    }
}

// ---------------------------------------------------------------------------
// Kernel 4: fusion MLP + final dot.  8 batches per block. grid=512, block=256.
// ---------------------------------------------------------------------------
__global__ __launch_bounds__(256) void k4_fusion(
    const float* __restrict__ FUE, const float* __restrict__ FIE,
    const float* __restrict__ POS_PE, const float* __restrict__ TP,
    const float* __restrict__ Wf1, const float* __restrict__ bf1,
    const float* __restrict__ Wf2, const float* __restrict__ bf2,
    const float* __restrict__ Wf3, float* __restrict__ out)
{
    const int b0 = blockIdx.x * 8;
    const int t = threadIdx.x;
    __shared__ float fin[8*128];
    __shared__ float fuel[8*64];
    __shared__ float h1[8*200];
    __shared__ float h2[8*80];
    __shared__ float prod[8*64];

    #pragma unroll
    for (int i = 0; i < 4; i++) {
        const int idx = t + i*256;
        const int g = idx >> 7, k = idx & 127;
        float v;
        if (k < 64)      v = FIE[(size_t)(b0+g)*64 + k];
        else if (k < 96) v = POS_PE[(size_t)(b0+g)*32 + (k-64)];
        else             v = TP[(size_t)(b0+g)*NP + (k-96)];
        fin[idx] = v;
    }
    #pragma unroll
    for (int i = 0; i < 2; i++) {
        const int idx = t + i*256;
        fuel[idx] = FUE[(size_t)b0*64 + idx];
    }
    __syncthreads();

    for (int idx = t; idx < 8*200; idx += 256) {
        const int g = idx / 200, j = idx - g*200;
        float acc = bf1[j];
        const float* fg = fin + g*128;
        #pragma unroll 4
        for (int k = 0; k < 128; k++) acc = fmaf(fg[k], Wf1[k*200 + j], acc);
        h1[g*200 + j] = fmaxf(acc, 0.f);
    }
    __syncthreads();
    for (int idx = t; idx < 8*80; idx += 256) {
        const int g = idx / 80, j = idx - g*80;
        float acc = bf2[j];
        const float* hg = h1 + g*200;
        #pragma unroll 4
        for (int k = 0; k < 200; k++) acc = fmaf(hg[k], Wf2[k*80 + j], acc);
        h2[g*80 + j] = fmaxf(acc, 0.f);
    }
    __syncthreads();
    for (int idx = t; idx < 8*64; idx += 256) {
        const int g = idx >> 6;
        const int e = idx & 63;
        float acc = 0.f;
        const float* hg = h2 + g*80;
        #pragma unroll
        for (int k = 0; k < 80; k++) acc = fmaf(hg[k], Wf3[k*64 + e], acc);
        prod[idx] = acc * fuel[idx];
    }
    __syncthreads();
    if (t < 8) {
        float s = 0.f;
        const float* pg = prod + t*64;
        #pragma unroll
        for (int e = 0; e < 64; e++) s += pg[e];
        out[b0 + t] = s;
    }
}

// ---------------------------------------------------------------------------
extern "C" void kernel_launch(void* const* d_in, const int* in_sizes, int n_in,
                              void* d_out, int out_size, void* d_ws, size_t ws_size,
                              hipStream_t stream)
{
    const float* item_emb       = (const float*)d_in[0];
    const float* user_emb       = (const float*)d_in[1];
    const float* W_if           = (const float*)d_in[2];
    const float* b_if           = (const float*)d_in[3];
    const float* W_uf           = (const float*)d_in[4];
    const float* b_uf           = (const float*)d_in[5];
    const float* Wp             = (const float*)d_in[6];
    const float* bp             = (const float*)d_in[7];
    const float* Wf1            = (const float*)d_in[8];
    const float* bf1            = (const float*)d_in[9];
    const float* Wf2            = (const float*)d_in[10];
    const float* bf2            = (const float*)d_in[11];
    const float* Wf3            = (const float*)d_in[12];
    const float* item_features  = (const float*)d_in[13];
    const float* user_features  = (const float*)d_in[14];
    const int*   user_id        = (const int*)d_in[15];
    const int*   target_item_id = (const int*)d_in[16];
    const int*   history_item_id= (const int*)d_in[17];
    const int*   history_len    = (const int*)d_in[18];
    const int*   pos_fb         = (const int*)d_in[19];
    const int*   pos_mask       = (const int*)d_in[20];
    const int*   neg_fb         = (const int*)d_in[21];
    const int*   neg_mask       = (const int*)d_in[22];

    float* out = (float*)d_out;
    float* ws  = (float*)d_ws;
    float* FUE = ws + WS_FUE;
    float* FIE = ws + WS_FIE;
    float* PIN = ws + WS_PIN;
    float* TP  = ws + WS_TP;
    float* PPE = ws + WS_PPE;

    k1_gather_attn<<<dim3(BN), dim3(256), 0, stream>>>(
        item_emb, user_emb, W_if, b_if, W_uf, b_uf,
        item_features, user_features, user_id, target_item_id,
        history_item_id, history_len, pos_fb, pos_mask,
        FUE, FIE, PIN);

    k2_prompt_gemm<<<dim3(25, 64), dim3(256), 0, stream>>>(PIN, Wp, bp, TP);

    k3_prompt_mlp<<<dim3(BN), dim3(256), 0, stream>>>(
        item_emb, pos_fb, pos_mask, neg_fb, neg_mask, TP, PPE, out);

    k4_fusion<<<dim3(BN/8), dim3(256), 0, stream>>>(
        FUE, FIE, PPE, TP, Wf1, bf1, Wf2, bf2, Wf3, out);
}

// Round 2
// 496.108 us; speedup vs baseline: 1.0239x; 1.0239x over previous
//
#include <hip/hip_runtime.h>
#include <hip/hip_bf16.h>
#include <math.h>

#define BN 4096
#define LH 200
#define LFB 100
#define ED 64
#define PD 32
#define HD 32
#define NP 3168   // P + PNET = 32 + 3136

// ws layout (floats)
#define WS_FUE 0                          // final_user_embed B*64
#define WS_FIE (WS_FUE + BN*ED)           // final_item_embed B*64
#define WS_PIN (WS_FIE + BN*ED)           // prompt_input B*64
#define WS_TP  (WS_PIN + BN*ED)           // total_prompt B*3168
#define WS_PPE (WS_TP + (size_t)BN*NP)    // pos_pe B*32

// ---------------------------------------------------------------------------
// Kernel 1: per-batch gathers, feature embeds, attention softmax pooling,
// pos-feedback masked mean.  grid=B, block=256.
// Latency-bound -> batch gathers (5-wide), shuffle softmax, VGPR headroom.
// ---------------------------------------------------------------------------
__global__ __launch_bounds__(256, 4) void k1_gather_attn(
    const float* __restrict__ item_emb, const float* __restrict__ user_emb,
    const float* __restrict__ W_if, const float* __restrict__ b_if,
    const float* __restrict__ W_uf, const float* __restrict__ b_uf,
    const float* __restrict__ item_features, const float* __restrict__ user_features,
    const int* __restrict__ user_id, const int* __restrict__ target_item_id,
    const int* __restrict__ hist_id, const int* __restrict__ hist_len,
    const int* __restrict__ pos_fb, const int* __restrict__ pos_mask,
    float* __restrict__ FUE, float* __restrict__ FIE, float* __restrict__ PIN)
{
    const int b = blockIdx.x;
    const int t = threadIdx.x;
    const int w = t >> 6;
    const int lane = t & 63;

    __shared__ __align__(16) float tgt[64];
    __shared__ float feats[256];
    __shared__ float ufe[64];
    __shared__ float attnS[256];
    __shared__ float wred[8];
    __shared__ float part[256];
    __shared__ float part2[256];
    __shared__ float cntw[4];

    const int tid_item = target_item_id[b];
    feats[t] = (t < 128) ? item_features[(size_t)b*128 + t]
                         : user_features[(size_t)b*128 + (t-128)];
    if (t < 64) tgt[t] = item_emb[(size_t)tid_item*64 + t];
    __syncthreads();

    // ---- attention scores: prefetch all 16 float4 of own hist row ----
    const int hl = hist_len[b];
    float sc = -1e9f;
    if (t < LH) {
        const int idx = hist_id[(size_t)b*LH + t];
        const float4* hp = (const float4*)(item_emb + (size_t)idx*64);
        float4 r[16];
        #pragma unroll
        for (int i = 0; i < 16; i++) r[i] = hp[i];
        const float4* tp = (const float4*)tgt;
        float acc = 0.f;
        #pragma unroll
        for (int i = 0; i < 16; i++) {
            const float4 t4 = tp[i];   // same addr all lanes -> LDS broadcast
            acc += r[i].x*t4.x + r[i].y*t4.y + r[i].z*t4.z + r[i].w*t4.w;
        }
        if (t < hl) sc = acc * 0.125f;
    }

    // ---- softmax via wave shuffles (200 valid scores) ----
    float m = sc;
    #pragma unroll
    for (int off = 32; off >= 1; off >>= 1) m = fmaxf(m, __shfl_xor(m, off, 64));
    if (lane == 0) wred[w] = m;
    __syncthreads();
    const float mx = fmaxf(fmaxf(wred[0], wred[1]), fmaxf(wred[2], wred[3]));
    const float ev = __expf(sc - mx);          // invalid lanes -> 0
    float s = ev;
    #pragma unroll
    for (int off = 32; off >= 1; off >>= 1) s += __shfl_xor(s, off, 64);
    if (lane == 0) wred[4 + w] = s;
    __syncthreads();
    const float S = wred[4] + wred[5] + wred[6] + wred[7];
    attnS[t] = ev / S;

    // ---- feature embeddings (wave 0: item, wave 1: user) ----
    if (w == 0) {
        float acc = b_if[lane];
        #pragma unroll 4
        for (int k = 0; k < 128; k++) acc = fmaf(feats[k], W_if[k*64 + lane], acc);
        FIE[(size_t)b*64 + lane] = tgt[lane] + 1.f / (1.f + __expf(-acc));
    } else if (w == 1) {
        float acc = b_uf[lane];
        #pragma unroll 4
        for (int k = 0; k < 128; k++) acc = fmaf(feats[128 + k], W_uf[k*64 + lane], acc);
        ufe[lane] = 1.f / (1.f + __expf(-acc));
    }
    __syncthreads();   // attnS visible

    // ---- pooled = sum_l attn[l]*hist[l][e], 50 l's per wave, batched 5 ----
    {
        float acc = 0.f;
        const int l0 = w * 50;
        const int* hid = hist_id + (size_t)b*LH;
        for (int g = 0; g < 10; g++) {
            const int base = l0 + g*5;
            int i0 = hid[base+0], i1 = hid[base+1], i2 = hid[base+2],
                i3 = hid[base+3], i4 = hid[base+4];
            float v0 = item_emb[(size_t)i0*64 + lane];
            float v1 = item_emb[(size_t)i1*64 + lane];
            float v2 = item_emb[(size_t)i2*64 + lane];
            float v3 = item_emb[(size_t)i3*64 + lane];
            float v4 = item_emb[(size_t)i4*64 + lane];
            acc = fmaf(attnS[base+0], v0, acc);
            acc = fmaf(attnS[base+1], v1, acc);
            acc = fmaf(attnS[base+2], v2, acc);
            acc = fmaf(attnS[base+3], v3, acc);
            acc = fmaf(attnS[base+4], v4, acc);
        }
        part[w*64 + lane] = acc;
    }

    // ---- pos-feedback masked mean, 25 l's per wave, batched 5 ----
    {
        float acc = 0.f, cnt = 0.f;
        const int l0 = w * 25;
        const int* pid = pos_fb + (size_t)b*LFB;
        const int* pmk = pos_mask + (size_t)b*LFB;
        for (int g = 0; g < 5; g++) {
            const int base = l0 + g*5;
            int m0 = pmk[base+0], m1 = pmk[base+1], m2 = pmk[base+2],
                m3 = pmk[base+3], m4 = pmk[base+4];
            int i0 = pid[base+0], i1 = pid[base+1], i2 = pid[base+2],
                i3 = pid[base+3], i4 = pid[base+4];
            float v0 = item_emb[(size_t)i0*64 + lane];
            float v1 = item_emb[(size_t)i1*64 + lane];
            float v2 = item_emb[(size_t)i2*64 + lane];
            float v3 = item_emb[(size_t)i3*64 + lane];
            float v4 = item_emb[(size_t)i4*64 + lane];
            float f0 = m0 ? 1.f : 0.f, f1 = m1 ? 1.f : 0.f, f2 = m2 ? 1.f : 0.f,
                  f3 = m3 ? 1.f : 0.f, f4 = m4 ? 1.f : 0.f;
            acc = fmaf(f0, v0, acc); acc = fmaf(f1, v1, acc);
            acc = fmaf(f2, v2, acc); acc = fmaf(f3, v3, acc);
            acc = fmaf(f4, v4, acc);
            cnt += f0 + f1 + f2 + f3 + f4;
        }
        part2[w*64 + lane] = acc;
        if (lane == 0) cntw[w] = cnt;
    }
    __syncthreads();

    if (t < 64) {
        const float c = cntw[0] + cntw[1] + cntw[2] + cntw[3];
        const float pooled = part[t] + part[64+t] + part[128+t] + part[192+t];
        PIN[(size_t)b*64 + t] = (part2[t] + part2[64+t] + part2[128+t] + part2[192+t]) / c;
        FUE[(size_t)b*64 + t] = user_emb[(size_t)user_id[b]*64 + t] + ufe[t] + pooled;
    }
}

// ---------------------------------------------------------------------------
// Kernel 2: total_prompt = relu(PIN (4096x64) @ Wp (64x3168) + bp)
// tile 64(m) x 128(n), K=64, 256 threads, 4x8 per thread. grid=(25,64)
// ---------------------------------------------------------------------------
__global__ __launch_bounds__(256) void k2_prompt_gemm(
    const float* __restrict__ PIN, const float* __restrict__ Wp,
    const float* __restrict__ bp, float* __restrict__ TP)
{
    __shared__ __align__(16) float As[64*65];    // [m][k], ld 65
    __shared__ __align__(16) float Bs[64*128];   // [k][n]
    const int t = threadIdx.x;
    const int m0 = blockIdx.y * 64;
    const int n0 = blockIdx.x * 128;
    {
        const int k = t & 63, ml = t >> 6;
        #pragma unroll
        for (int i = 0; i < 16; i++) {
            const int m = ml + i*4;
            As[m*65 + k] = PIN[(size_t)(m0+m)*64 + k];
        }
    }
    {
        const int n = t & 127, kl = t >> 7;
        const int gn = n0 + n;
        #pragma unroll
        for (int i = 0; i < 32; i++) {
            const int k = kl + i*2;
            Bs[k*128 + n] = (gn < NP) ? Wp[(size_t)k*NP + gn] : 0.f;
        }
    }
    __syncthreads();
    const int tx = t & 15, ty = t >> 4;
    float acc[4][8];
    #pragma unroll
    for (int i = 0; i < 4; i++)
        #pragma unroll
        for (int j = 0; j < 8; j++) acc[i][j] = 0.f;

    #pragma unroll 4
    for (int k = 0; k < 64; k++) {
        float a[4];
        #pragma unroll
        for (int i = 0; i < 4; i++) a[i] = As[(ty*4+i)*65 + k];
        const float4 b0 = *(const float4*)&Bs[k*128 + tx*8];
        const float4 b1 = *(const float4*)&Bs[k*128 + tx*8 + 4];
        #pragma unroll
        for (int i = 0; i < 4; i++) {
            acc[i][0] = fmaf(a[i], b0.x, acc[i][0]);
            acc[i][1] = fmaf(a[i], b0.y, acc[i][1]);
            acc[i][2] = fmaf(a[i], b0.z, acc[i][2]);
            acc[i][3] = fmaf(a[i], b0.w, acc[i][3]);
            acc[i][4] = fmaf(a[i], b1.x, acc[i][4]);
            acc[i][5] = fmaf(a[i], b1.y, acc[i][5]);
            acc[i][6] = fmaf(a[i], b1.z, acc[i][6]);
            acc[i][7] = fmaf(a[i], b1.w, acc[i][7]);
        }
    }
    #pragma unroll
    for (int i = 0; i < 4; i++) {
        const int m = m0 + ty*4 + i;
        #pragma unroll
        for (int j = 0; j < 8; j++) {
            const int n = n0 + tx*8 + j;
            if (n < NP) TP[(size_t)m*NP + n] = fmaxf(acc[i][j] + bp[n], 0.f);
        }
    }
}

// ---------------------------------------------------------------------------
// Kernel 3: prompt hypernetwork MLP.  grid=B, block=128.
// pnet staged in LDS once; thread t<100 does pos[t] AND neg[t] sharing each
// LDS weight broadcast (same-address b128 -> free).  VALU-bound target.
// ---------------------------------------------------------------------------
__global__ __launch_bounds__(128) void k3_prompt_mlp(
    const float* __restrict__ item_emb,
    const int* __restrict__ pos_fb, const int* __restrict__ pos_mask,
    const int* __restrict__ neg_fb, const int* __restrict__ neg_mask,
    const float* __restrict__ TP,
    float* __restrict__ POS_PE, float* __restrict__ out)
{
    const int b = blockIdx.x;
    const int t = threadIdx.x;
    __shared__ __align__(16) float pns[3136];      // w1|b1|w2|b2
    __shared__ float scratch[128*33];

    // stage pnet (3136 floats = 784 float4), coalesced
    {
        const float4* pn4 = (const float4*)(TP + (size_t)b*NP + 32);
        float4* d4 = (float4*)pns;
        for (int i = t; i < 784; i += 128) d4[i] = pn4[i];
    }

    bool ap = false, an = false;
    int ip = 0, in_ = 0;
    if (t < LFB) {
        ap  = pos_mask[(size_t)b*LFB + t] != 0;
        an  = neg_mask[(size_t)b*LFB + t] != 0;
        ip  = pos_fb[(size_t)b*LFB + t];
        in_ = neg_fb[(size_t)b*LFB + t];
    }
    const float4* urp = (const float4*)(item_emb + (size_t)ip*64);
    const float4* urn = (const float4*)(item_emb + (size_t)in_*64);
    __syncthreads();

    // layer 1: h[e] = relu(sum_k u[k]*w1[k][e] + b1[e]);  w1[k][e]=pns[k*32+e]
    float hp[32], hn[32];
    {
        const float4* b1v = (const float4*)&pns[2048];
        #pragma unroll
        for (int eb = 0; eb < 8; eb++) {
            const float4 bv = b1v[eb];
            hp[eb*4+0] = bv.x; hp[eb*4+1] = bv.y; hp[eb*4+2] = bv.z; hp[eb*4+3] = bv.w;
            hn[eb*4+0] = bv.x; hn[eb*4+1] = bv.y; hn[eb*4+2] = bv.z; hn[eb*4+3] = bv.w;
        }
    }
    #pragma unroll 4
    for (int kc = 0; kc < 16; kc++) {
        const float4 up4 = urp[kc];
        const float4 un4 = urn[kc];
        const float usp[4] = {up4.x, up4.y, up4.z, up4.w};
        const float usn[4] = {un4.x, un4.y, un4.z, un4.w};
        #pragma unroll
        for (int j = 0; j < 4; j++) {
            const float ukp = usp[j], ukn = usn[j];
            const float4* wr = (const float4*)&pns[(kc*4 + j)*32];
            #pragma unroll
            for (int eb = 0; eb < 8; eb++) {
                const float4 wv = wr[eb];     // broadcast read
                hp[eb*4+0] = fmaf(ukp, wv.x, hp[eb*4+0]);
                hp[eb*4+1] = fmaf(ukp, wv.y, hp[eb*4+1]);
                hp[eb*4+2] = fmaf(ukp, wv.z, hp[eb*4+2]);
                hp[eb*4+3] = fmaf(ukp, wv.w, hp[eb*4+3]);
                hn[eb*4+0] = fmaf(ukn, wv.x, hn[eb*4+0]);
                hn[eb*4+1] = fmaf(ukn, wv.y, hn[eb*4+1]);
                hn[eb*4+2] = fmaf(ukn, wv.z, hn[eb*4+2]);
                hn[eb*4+3] = fmaf(ukn, wv.w, hn[eb*4+3]);
            }
        }
    }
    #pragma unroll
    for (int e = 0; e < 32; e++) { hp[e] = fmaxf(hp[e], 0.f); hn[e] = fmaxf(hn[e], 0.f); }

    // layer 2: o[p] = sum_e h[e]*w2[e][p] + b2[p];  w2[e][p]=pns[2080+e*32+p]
    float op[32], on[32];
    {
        const float4* b2v = (const float4*)&pns[3104];
        #pragma unroll
        for (int pb = 0; pb < 8; pb++) {
            const float4 bv = b2v[pb];
            op[pb*4+0] = bv.x; op[pb*4+1] = bv.y; op[pb*4+2] = bv.z; op[pb*4+3] = bv.w;
            on[pb*4+0] = bv.x; on[pb*4+1] = bv.y; on[pb*4+2] = bv.z; on[pb*4+3] = bv.w;
        }
    }
    #pragma unroll
    for (int e = 0; e < 32; e++) {
        const float hep = hp[e], hen = hn[e];
        const float4* wr = (const float4*)&pns[2080 + e*32];
        #pragma unroll
        for (int pb = 0; pb < 8; pb++) {
            const float4 wv = wr[pb];         // broadcast read
            op[pb*4+0] = fmaf(hep, wv.x, op[pb*4+0]);
            op[pb*4+1] = fmaf(hep, wv.y, op[pb*4+1]);
            op[pb*4+2] = fmaf(hep, wv.z, op[pb*4+2]);
            op[pb*4+3] = fmaf(hep, wv.w, op[pb*4+3]);
            on[pb*4+0] = fmaf(hen, wv.x, on[pb*4+0]);
            on[pb*4+1] = fmaf(hen, wv.y, on[pb*4+1]);
            on[pb*4+2] = fmaf(hen, wv.z, on[pb*4+2]);
            on[pb*4+3] = fmaf(hen, wv.w, on[pb*4+3]);
        }
    }

    // masked reduce pos
    #pragma unroll
    for (int p = 0; p < 32; p++) scratch[t*33 + p] = ap ? op[p] : 0.f;
    __syncthreads();
    #pragma unroll
    for (int s = 64; s >= 1; s >>= 1) {
        for (int i = t; i < s*32; i += 128) {
            const int r = i >> 5, p = i & 31;
            scratch[r*33 + p] += scratch[(r+s)*33 + p];
        }
        __syncthreads();
    }
    float pp = 0.f;
    if (t < 32) pp = scratch[t];
    __syncthreads();

    // masked reduce neg
    #pragma unroll
    for (int p = 0; p < 32; p++) scratch[t*33 + p] = an ? on[p] : 0.f;
    __syncthreads();
    #pragma unroll
    for (int s = 64; s >= 1; s >>= 1) {
        for (int i = t; i < s*32; i += 128) {
            const int r = i >> 5, p = i & 31;
            scratch[r*33 + p] += scratch[(r+s)*33 + p];
        }
        __syncthreads();
    }
    if (t < 32) {
        const float np = scratch[t];
        POS_PE[(size_t)b*32 + t] = pp;
        const float x = np - pp;                   // -(pos - neg)
        out[BN + (size_t)b*32 + t] = fmaxf(x, 0.f) + log1pf(__expf(-fabsf(x)));
    }
}

// ---------------------------------------------------------------------------
// Kernel 4: fusion MLP + final dot.  8 batches per block. grid=512, block=256.
// ---------------------------------------------------------------------------
__global__ __launch_bounds__(256) void k4_fusion(
    const float* __restrict__ FUE, const float* __restrict__ FIE,
    const float* __restrict__ POS_PE, const float* __restrict__ TP,
    const float* __restrict__ Wf1, const float* __restrict__ bf1,
    const float* __restrict__ Wf2, const float* __restrict__ bf2,
    const float* __restrict__ Wf3, float* __restrict__ out)
{
    const int b0 = blockIdx.x * 8;
    const int t = threadIdx.x;
    __shared__ float fin[8*128];
    __shared__ float fuel[8*64];
    __shared__ float h1[8*200];
    __shared__ float h2[8*80];
    __shared__ float prod[8*64];

    #pragma unroll
    for (int i = 0; i < 4; i++) {
        const int idx = t + i*256;
        const int g = idx >> 7, k = idx & 127;
        float v;
        if (k < 64)      v = FIE[(size_t)(b0+g)*64 + k];
        else if (k < 96) v = POS_PE[(size_t)(b0+g)*32 + (k-64)];
        else             v = TP[(size_t)(b0+g)*NP + (k-96)];
        fin[idx] = v;
    }
    #pragma unroll
    for (int i = 0; i < 2; i++) {
        const int idx = t + i*256;
        fuel[idx] = FUE[(size_t)b0*64 + idx];
    }
    __syncthreads();

    for (int idx = t; idx < 8*200; idx += 256) {
        const int g = idx / 200, j = idx - g*200;
        float acc = bf1[j];
        const float* fg = fin + g*128;
        #pragma unroll 4
        for (int k = 0; k < 128; k++) acc = fmaf(fg[k], Wf1[k*200 + j], acc);
        h1[g*200 + j] = fmaxf(acc, 0.f);
    }
    __syncthreads();
    for (int idx = t; idx < 8*80; idx += 256) {
        const int g = idx / 80, j = idx - g*80;
        float acc = bf2[j];
        const float* hg = h1 + g*200;
        #pragma unroll 4
        for (int k = 0; k < 200; k++) acc = fmaf(hg[k], Wf2[k*80 + j], acc);
        h2[g*80 + j] = fmaxf(acc, 0.f);
    }
    __syncthreads();
    for (int idx = t; idx < 8*64; idx += 256) {
        const int g = idx >> 6;
        const int e = idx & 63;
        float acc = 0.f;
        const float* hg = h2 + g*80;
        #pragma unroll
        for (int k = 0; k < 80; k++) acc = fmaf(hg[k], Wf3[k*64 + e], acc);
        prod[idx] = acc * fuel[idx];
    }
    __syncthreads();
    if (t < 8) {
        float s = 0.f;
        const float* pg = prod + t*64;
        #pragma unroll
        for (int e = 0; e < 64; e++) s += pg[e];
        out[b0 + t] = s;
    }
}

// ---------------------------------------------------------------------------
extern "C" void kernel_launch(void* const* d_in, const int* in_sizes, int n_in,
                              void* d_out, int out_size, void* d_ws, size_t ws_size,
                              hipStream_t stream)
{
    const float* item_emb       = (const float*)d_in[0];
    const float* user_emb       = (const float*)d_in[1];
    const float* W_if           = (const float*)d_in[2];
    const float* b_if           = (const float*)d_in[3];
    const float* W_uf           = (const float*)d_in[4];
    const float* b_uf           = (const float*)d_in[5];
    const float* Wp             = (const float*)d_in[6];
    const float* bp             = (const float*)d_in[7];
    const float* Wf1            = (const float*)d_in[8];
    const float* bf1            = (const float*)d_in[9];
    const float* Wf2            = (const float*)d_in[10];
    const float* bf2            = (const float*)d_in[11];
    const float* Wf3            = (const float*)d_in[12];
    const float* item_features  = (const float*)d_in[13];
    const float* user_features  = (const float*)d_in[14];
    const int*   user_id        = (const int*)d_in[15];
    const int*   target_item_id = (const int*)d_in[16];
    const int*   history_item_id= (const int*)d_in[17];
    const int*   history_len    = (const int*)d_in[18];
    const int*   pos_fb         = (const int*)d_in[19];
    const int*   pos_mask       = (const int*)d_in[20];
    const int*   neg_fb         = (const int*)d_in[21];
    const int*   neg_mask       = (const int*)d_in[22];

    float* out = (float*)d_out;
    float* ws  = (float*)d_ws;
    float* FUE = ws + WS_FUE;
    float* FIE = ws + WS_FIE;
    float* PIN = ws + WS_PIN;
    float* TP  = ws + WS_TP;
    float* PPE = ws + WS_PPE;

    k1_gather_attn<<<dim3(BN), dim3(256), 0, stream>>>(
        item_emb, user_emb, W_if, b_if, W_uf, b_uf,
        item_features, user_features, user_id, target_item_id,
        history_item_id, history_len, pos_fb, pos_mask,
        FUE, FIE, PIN);

    k2_prompt_gemm<<<dim3(25, 64), dim3(256), 0, stream>>>(PIN, Wp, bp, TP);

    k3_prompt_mlp<<<dim3(BN), dim3(128), 0, stream>>>(
        item_emb, pos_fb, pos_mask, neg_fb, neg_mask, TP, PPE, out);

    k4_fusion<<<dim3(BN/8), dim3(256), 0, stream>>>(
        FUE, FIE, PPE, TP, Wf1, bf1, Wf2, bf2, Wf3, out);
}